// Round 1
// baseline (337.642 us; speedup 1.0000x reference)
//
#include <hip/hip_runtime.h>
#include <hip/hip_bf16.h>
#include <stdint.h>

#define NB 8
#define LL 4096
#define LQ 2048
#define DD 128

typedef __attribute__((ext_vector_type(8))) short short8;   // bf16x8 MFMA frag
typedef __attribute__((ext_vector_type(4))) float f4;

__device__ __forceinline__ float dot4(f4 a, f4 b) {
    return a.x * b.x + a.y * b.y + a.z * b.z + a.w * b.w;
}

// ---------------------------------------------------------------------------
// Kernel A: proj = x@W^T + b (f32), q = avgpool2(x)@W^T + b (f32)
//   writes: proj bf16 [B][4096][128], projT bf16 [B][128][4096],
//           q bf16 [B][2048][128], q f32 -> d_out, psq/qsq from bf16 values
// blocks [0,1024): proj rows (32/block); [1024,1536): q rows (32/block)
// ---------------------------------------------------------------------------
__global__ __launch_bounds__(256) void proj_kernel(
    const float* __restrict__ x, const float* __restrict__ W,
    const float* __restrict__ bias,
    __hip_bfloat16* __restrict__ proj, __hip_bfloat16* __restrict__ projT,
    __hip_bfloat16* __restrict__ qb, float* __restrict__ qf,
    float* __restrict__ psq, float* __restrict__ qsq)
{
    __shared__ float xs[32][132];            // staged (pooled) input rows
    __shared__ __hip_bfloat16 ts[128][40];   // transpose staging (proj mode)

    const int bid = blockIdx.x;
    const int tid = threadIdx.x;
    const bool qmode = bid >= (NB * LL / 32);   // >= 1024

    // ---- stage 32 input rows (or pooled rows) into LDS ----
    {
        const int r = tid >> 3;            // 0..31
        const int c = (tid & 7) * 16;      // 0..112
        if (!qmode) {
            const float* src = x + (size_t)(bid * 32 + r) * DD + c;
            #pragma unroll
            for (int i = 0; i < 4; ++i)
                *(f4*)&xs[r][c + i * 4] = *(const f4*)&src[i * 4];
        } else {
            const int qr = (bid - NB * LL / 32) * 32 + r;   // global q row
            const int b = qr / LQ, l = qr % LQ;
            const float* s0 = x + ((size_t)b * LL + 2 * l) * DD + c;
            const float* s1 = s0 + DD;
            #pragma unroll
            for (int i = 0; i < 4; ++i) {
                f4 a = *(const f4*)&s0[i * 4];
                f4 bb = *(const f4*)&s1[i * 4];
                *(f4*)&xs[r][c + i * 4] = (a + bb) * 0.5f;
            }
        }
    }
    __syncthreads();

    const int egrp = tid & 15, rslot = tid >> 4;
    const int e0 = egrp * 8;
    const int r0 = rslot * 2;

    float acc0[8], acc1[8];
    #pragma unroll
    for (int j = 0; j < 8; ++j) { acc0[j] = bias[e0 + j]; acc1[j] = acc0[j]; }

    #pragma unroll 4
    for (int d4 = 0; d4 < 32; ++d4) {
        f4 xa = *(const f4*)&xs[r0][d4 * 4];
        f4 xb = *(const f4*)&xs[r0 + 1][d4 * 4];
        #pragma unroll
        for (int j = 0; j < 8; ++j) {
            f4 w = *(const f4*)&W[(size_t)(e0 + j) * DD + d4 * 4];
            acc0[j] += dot4(xa, w);
            acc1[j] += dot4(xb, w);
        }
    }

    // cast to bf16; norms computed from the bf16-rounded values (consistency!)
    __hip_bfloat16 h0[8], h1[8];
    float s0 = 0.f, s1 = 0.f;
    #pragma unroll
    for (int j = 0; j < 8; ++j) {
        h0[j] = __float2bfloat16(acc0[j]);
        h1[j] = __float2bfloat16(acc1[j]);
        float v0 = __bfloat162float(h0[j]);
        float v1 = __bfloat162float(h1[j]);
        s0 += v0 * v0;
        s1 += v1 * v1;
    }
    #pragma unroll
    for (int m = 1; m < 16; m <<= 1) {
        s0 += __shfl_xor(s0, m);
        s1 += __shfl_xor(s1, m);
    }

    if (!qmode) {
        const int gr0 = bid * 32 + r0;
        *(short8*)&proj[(size_t)gr0 * DD + e0] = *(short8*)h0;
        *(short8*)&proj[(size_t)(gr0 + 1) * DD + e0] = *(short8*)h1;
        if (egrp == 0) { psq[gr0] = s0; psq[gr0 + 1] = s1; }
        // stage transpose
        #pragma unroll
        for (int j = 0; j < 8; ++j) {
            ts[e0 + j][r0] = h0[j];
            ts[e0 + j][r0 + 1] = h1[j];
        }
        __syncthreads();
        // coalesced projT writes: thread t -> (e = t>>1, half = t&1), 16 elems
        const int e = tid >> 1, half = tid & 1;
        const int rb = bid * 32;
        const int b = rb / LL, lrow = rb % LL;
        __hip_bfloat16* dst = projT + ((size_t)b * DD + e) * LL + lrow + half * 16;
        *(short8*)dst = *(short8*)&ts[e][half * 16];
        *(short8*)(dst + 8) = *(short8*)&ts[e][half * 16 + 8];
    } else {
        const int gq0 = (bid - NB * LL / 32) * 32 + r0;
        *(short8*)&qb[(size_t)gq0 * DD + e0] = *(short8*)h0;
        *(short8*)&qb[(size_t)(gq0 + 1) * DD + e0] = *(short8*)h1;
        // f32 q output (full precision)
        f4 a0 = {acc0[0], acc0[1], acc0[2], acc0[3]};
        f4 a1 = {acc0[4], acc0[5], acc0[6], acc0[7]};
        f4 b0 = {acc1[0], acc1[1], acc1[2], acc1[3]};
        f4 b1 = {acc1[4], acc1[5], acc1[6], acc1[7]};
        *(f4*)&qf[(size_t)gq0 * DD + e0] = a0;
        *(f4*)&qf[(size_t)gq0 * DD + e0 + 4] = a1;
        *(f4*)&qf[(size_t)(gq0 + 1) * DD + e0] = b0;
        *(f4*)&qf[(size_t)(gq0 + 1) * DD + e0 + 4] = b1;
        if (egrp == 0) { qsq[gq0] = s0; qsq[gq0 + 1] = s1; }
    }
}

// ---------------------------------------------------------------------------
// Kernel B: fused  S = q.proj^T ; sim = exp(-sqrt(max(qsq+psq-2S,0))) ;
//           O += sim @ proj   (flash-style, no softmax state)
// block: 32 q-rows, 4 waves; key tiles of 64; double-buffered sim in LDS
// ---------------------------------------------------------------------------
__global__ __launch_bounds__(256) void fused_kernel(
    const __hip_bfloat16* __restrict__ proj, const __hip_bfloat16* __restrict__ projT,
    const __hip_bfloat16* __restrict__ qb, const float* __restrict__ psq,
    const float* __restrict__ qsq, float* __restrict__ outk, float* __restrict__ outv)
{
    __shared__ __hip_bfloat16 simbuf[2][32][72];
    __shared__ float otile[32][132];

    const int bid = blockIdx.x;
    const int b = bid >> 6;        // 64 blocks per batch
    const int qt = bid & 63;
    const int qrow0 = qt * 32;
    const int tid = threadIdx.x;
    const int w = tid >> 6;        // wave 0..3
    const int lane = tid & 63;
    const int lr = lane & 15, lh = lane >> 4;

    // q A-frags for the whole block (K=128 -> 4 ksteps, 2 mtiles)
    short8 aq[2][4];
    const __hip_bfloat16* qbase = qb + ((size_t)b * LQ + qrow0) * DD;
    #pragma unroll
    for (int mt = 0; mt < 2; ++mt)
        #pragma unroll
        for (int ks = 0; ks < 4; ++ks)
            aq[mt][ks] = *(const short8*)&qbase[(size_t)(mt * 16 + lr) * DD + ks * 32 + lh * 8];

    float qs[2][4];
    #pragma unroll
    for (int mt = 0; mt < 2; ++mt)
        #pragma unroll
        for (int r = 0; r < 4; ++r)
            qs[mt][r] = qsq[b * LQ + qrow0 + mt * 16 + lh * 4 + r];

    f4 oc[2][2] = {};   // [mtile][dtile], wave's d range = [w*32, w*32+32)

    const __hip_bfloat16* pjb = proj + (size_t)b * LL * DD;
    const __hip_bfloat16* ptb = projT + (size_t)b * DD * LL;
    const float* psb = psq + b * LL;

    for (int kt = 0; kt < LL / 64; ++kt) {
        const int keyw = kt * 64 + w * 16;   // this wave's 16 keys for GEMM1
        // ---- GEMM1: S[0:32][keyw:keyw+16] ----
        f4 s[2] = {};
        #pragma unroll
        for (int ks = 0; ks < 4; ++ks) {
            short8 bk = *(const short8*)&pjb[(size_t)(keyw + lr) * DD + ks * 32 + lh * 8];
            s[0] = __builtin_amdgcn_mfma_f32_16x16x32_bf16(aq[0][ks], bk, s[0], 0, 0, 0);
            s[1] = __builtin_amdgcn_mfma_f32_16x16x32_bf16(aq[1][ks], bk, s[1], 0, 0, 0);
        }
        // ---- transform -> sim (bf16) -> LDS ----
        const float pn = psb[keyw + lr];
        #pragma unroll
        for (int mt = 0; mt < 2; ++mt) {
            #pragma unroll
            for (int r = 0; r < 4; ++r) {
                float power = qs[mt][r] + pn - 2.0f * s[mt][r];
                float dist = sqrtf(fmaxf(power, 0.0f));
                float sim = __expf(-dist);
                simbuf[kt & 1][mt * 16 + lh * 4 + r][w * 16 + lr] = __float2bfloat16(sim);
            }
        }
        __syncthreads();
        // ---- GEMM2: O += sim @ proj (contract over 64 keys) ----
        const int kb = kt * 64;
        #pragma unroll
        for (int kk = 0; kk < 2; ++kk) {
            short8 sa0 = *(const short8*)&simbuf[kt & 1][lr][kk * 32 + lh * 8];
            short8 sa1 = *(const short8*)&simbuf[kt & 1][16 + lr][kk * 32 + lh * 8];
            #pragma unroll
            for (int dt = 0; dt < 2; ++dt) {
                short8 bv = *(const short8*)&ptb[(size_t)(w * 32 + dt * 16 + lr) * LL + kb + kk * 32 + lh * 8];
                oc[0][dt] = __builtin_amdgcn_mfma_f32_16x16x32_bf16(sa0, bv, oc[0][dt], 0, 0, 0);
                oc[1][dt] = __builtin_amdgcn_mfma_f32_16x16x32_bf16(sa1, bv, oc[1][dt], 0, 0, 0);
            }
        }
    }

    // ---- epilogue: transpose O through LDS for coalesced f32 stores ----
    __syncthreads();
    #pragma unroll
    for (int mt = 0; mt < 2; ++mt)
        #pragma unroll
        for (int dt = 0; dt < 2; ++dt)
            #pragma unroll
            for (int r = 0; r < 4; ++r)
                otile[mt * 16 + lh * 4 + r][w * 32 + dt * 16 + lr] = oc[mt][dt][r];
    __syncthreads();

    const int row = tid >> 3;
    const int c0 = (tid & 7) * 16;
    float* dk = outk + ((size_t)b * LQ + qrow0 + row) * DD + c0;
    float* dv = outv + ((size_t)b * LQ + qrow0 + row) * DD + c0;
    #pragma unroll
    for (int i = 0; i < 4; ++i) {
        f4 v = *(const f4*)&otile[row][c0 + i * 4];
        *(f4*)&dk[i * 4] = v;
        *(f4*)&dv[i * 4] = v;
    }
}

extern "C" void kernel_launch(void* const* d_in, const int* in_sizes, int n_in,
                              void* d_out, int out_size, void* d_ws, size_t ws_size,
                              hipStream_t stream) {
    const float* x = (const float*)d_in[0];
    const float* W = (const float*)d_in[1];
    const float* bias = (const float*)d_in[2];

    float* out = (float*)d_out;
    const size_t NQ = (size_t)NB * LQ * DD;    // 2,097,152 per output tensor
    float* qf = out;            // output 0: q
    float* outk = out + NQ;     // output 1: k
    float* outv = out + 2 * NQ; // output 2: v

    char* ws = (char*)d_ws;
    __hip_bfloat16* proj  = (__hip_bfloat16*)ws;                          // 8 MB
    __hip_bfloat16* projT = (__hip_bfloat16*)(ws + 8u * 1024 * 1024);     // 8 MB
    __hip_bfloat16* qb    = (__hip_bfloat16*)(ws + 16u * 1024 * 1024);    // 4 MB
    float* psq            = (float*)(ws + 20u * 1024 * 1024);             // 128 KB
    float* qsq            = (float*)(ws + 20u * 1024 * 1024 + 256u * 1024); // 64 KB

    hipLaunchKernelGGL(proj_kernel, dim3((NB * LL + NB * LQ) / 32), dim3(256), 0, stream,
                       x, W, bias, proj, projT, qb, qf, psq, qsq);
    hipLaunchKernelGGL(fused_kernel, dim3(NB * (LQ / 32)), dim3(256), 0, stream,
                       proj, projT, qb, psq, qsq, outk, outv);
}

// Round 2
// 166.141 us; speedup vs baseline: 2.0323x; 2.0323x over previous
//
#include <hip/hip_runtime.h>
#include <hip/hip_bf16.h>
#include <stdint.h>

#define NB 8
#define LL 4096
#define LQ 2048
#define DD 128

typedef __attribute__((ext_vector_type(8))) short short8;   // bf16x8 MFMA frag
typedef __attribute__((ext_vector_type(4))) float f4;
typedef __attribute__((ext_vector_type(2))) unsigned int u2;

__device__ __forceinline__ short8 pack8(const float* v) {
    __hip_bfloat16 h[8];
    #pragma unroll
    for (int j = 0; j < 8; ++j) h[j] = __float2bfloat16(v[j]);
    return *(short8*)h;
}

// ---------------------------------------------------------------------------
// Kernel A (MFMA): proj = x@W^T + b, q = avgpool2(x)@W^T + b
//   768 tiles of 64 rows: tiles [0,512) proj rows, [512,768) q rows.
//   Per block: W staged bf16 in swizzled LDS; 4 waves x 16 rows x 128 cols.
//   Outputs: proj bf16, projT bf16 (LDS transpose), qb bf16, q f32 (d_out),
//            psq/qsq computed from the bf16-rounded values (consistency).
// ---------------------------------------------------------------------------
__global__ __launch_bounds__(256) void projA_kernel(
    const float* __restrict__ x, const float* __restrict__ W,
    const float* __restrict__ bias,
    __hip_bfloat16* __restrict__ proj, __hip_bfloat16* __restrict__ projT,
    __hip_bfloat16* __restrict__ qb, float* __restrict__ qf,
    float* __restrict__ psq, float* __restrict__ qsq)
{
    __shared__ __hip_bfloat16 Wlds[128 * 128];      // 32 KB, XOR-swizzled
    __shared__ __hip_bfloat16 Tt[4][128 * 16];      // 4 KB per-wave transpose tile

    const int tid = threadIdx.x;
    const int lane = tid & 63, w = tid >> 6;
    const int lr = lane & 15, lh = lane >> 4;       // frag row / k-chunk

    // ---- stage W -> bf16 swizzled LDS (fully coalesced f32 reads) ----
    #pragma unroll
    for (int k = 0; k < 16; ++k) {
        const int f = k * 1024 + tid * 4;           // flat f32 index
        const int e = f >> 7, col = f & 127;
        f4 v = *(const f4*)&W[f];
        __hip_bfloat16 h[4];
        #pragma unroll
        for (int j = 0; j < 4; ++j) h[j] = __float2bfloat16(v[j]);
        const int byte = e * 256 + (((col * 2)) ^ ((e & 7) << 4));
        *(u2*)((char*)Wlds + byte) = *(u2*)h;
    }
    float bv[8];
    #pragma unroll
    for (int nt = 0; nt < 8; ++nt) bv[nt] = bias[nt * 16 + lr];
    __syncthreads();

    const int tile = blockIdx.x;                    // 768 blocks, 1 tile each
    const int row0 = tile * 64 + w * 16;            // wave's 16 rows
    const bool qmode = tile >= (NB * LL / 64);      // >= 512

    // ---- A-frags: lane lr -> row row0+lr, 8 bf16 at k = ks*32 + lh*8 ----
    short8 a[4];
    if (!qmode) {
        const float* src = x + (size_t)(row0 + lr) * DD;
        #pragma unroll
        for (int ks = 0; ks < 4; ++ks) {
            float t[8];
            *(f4*)&t[0] = *(const f4*)&src[ks * 32 + lh * 8];
            *(f4*)&t[4] = *(const f4*)&src[ks * 32 + lh * 8 + 4];
            a[ks] = pack8(t);
        }
    } else {
        const int gq = row0 - NB * LL + lr;         // global q row
        const int b = gq >> 11, l = gq & 2047;
        const float* s0 = x + ((size_t)b * LL + 2 * l) * DD;
        #pragma unroll
        for (int ks = 0; ks < 4; ++ks) {
            float t[8];
            f4 u0 = *(const f4*)&s0[ks * 32 + lh * 8];
            f4 u1 = *(const f4*)&s0[ks * 32 + lh * 8 + 4];
            f4 v0 = *(const f4*)&s0[DD + ks * 32 + lh * 8];
            f4 v1 = *(const f4*)&s0[DD + ks * 32 + lh * 8 + 4];
            *(f4*)&t[0] = (u0 + v0) * 0.5f;
            *(f4*)&t[4] = (u1 + v1) * 0.5f;
            a[ks] = pack8(t);
        }
    }

    // ---- MFMA: 8 ntiles x 4 ksteps ----
    f4 acc[8] = {};
    #pragma unroll
    for (int nt = 0; nt < 8; ++nt) {
        const int e = nt * 16 + lr;
        #pragma unroll
        for (int ks = 0; ks < 4; ++ks) {
            const int byte = e * 256 + ((ks * 64 + lh * 16) ^ ((lr & 7) << 4));
            short8 bk = *(const short8*)((char*)Wlds + byte);
            acc[nt] = __builtin_amdgcn_mfma_f32_16x16x32_bf16(a[ks], bk, acc[nt], 0, 0, 0);
        }
    }

    // ---- epilogue: C[m= lh*4+r][e= nt*16+lr] ----
    __hip_bfloat16 h[8][4];
    f4 rn = {0.f, 0.f, 0.f, 0.f};
    #pragma unroll
    for (int nt = 0; nt < 8; ++nt)
        #pragma unroll
        for (int r = 0; r < 4; ++r) {
            float v = acc[nt][r] + bv[nt];
            acc[nt][r] = v;                          // keep f32 for q output
            h[nt][r] = __float2bfloat16(v);
            float vb = __bfloat162float(h[nt][r]);
            rn[r] += vb * vb;
        }
    #pragma unroll
    for (int m = 1; m < 16; m <<= 1) {
        #pragma unroll
        for (int r = 0; r < 4; ++r) rn[r] += __shfl_xor(rn[r], m);
    }

    if (!qmode) {
        const int gr = row0;                         // global proj row base
        #pragma unroll
        for (int nt = 0; nt < 8; ++nt)
            #pragma unroll
            for (int r = 0; r < 4; ++r)
                proj[(size_t)(gr + lh * 4 + r) * DD + nt * 16 + lr] = h[nt][r];
        if (lr == 0) *(f4*)&psq[gr + lh * 4] = rn;
        // transpose tile: lane writes col e = nt*16+lr, rows lh*4..+3 (8B)
        #pragma unroll
        for (int nt = 0; nt < 8; ++nt) {
            __hip_bfloat16 p[4] = {h[nt][0], h[nt][1], h[nt][2], h[nt][3]};
            *(u2*)((char*)&Tt[w][0] + (nt * 16 + lr) * 32 + lh * 8) = *(u2*)p;
        }
        // wave-private LDS: compiler-inserted lgkmcnt orders write->read
        const int b = gr >> 12, l0 = gr & 4095;
        #pragma unroll
        for (int i = 0; i < 2; ++i) {
            const int e = lane + i * 64;
            short8 t0 = *(const short8*)&Tt[w][e * 16];
            short8 t1 = *(const short8*)&Tt[w][e * 16 + 8];
            __hip_bfloat16* dst = projT + ((size_t)(b * DD + e)) * LL + l0;
            *(short8*)dst = t0;
            *(short8*)(dst + 8) = t1;
        }
    } else {
        const int gq = row0 - NB * LL;               // q row base
        #pragma unroll
        for (int nt = 0; nt < 8; ++nt)
            #pragma unroll
            for (int r = 0; r < 4; ++r) {
                const size_t idx = (size_t)(gq + lh * 4 + r) * DD + nt * 16 + lr;
                qb[idx] = h[nt][r];
                qf[idx] = acc[nt][r];
            }
        if (lr == 0) *(f4*)&qsq[gq + lh * 4] = rn;
    }
}

// ---------------------------------------------------------------------------
// Kernel B: fused  S = q.proj^T ; sim = exp(-sqrt(max(qsq+psq-2S,0))) ;
//           O += sim @ proj   (flash-style, no softmax state)
// XCD-pinned: b = bid&7 so each XCD's L2 holds exactly one batch's proj/projT
// ---------------------------------------------------------------------------
__global__ __launch_bounds__(256) void fused_kernel(
    const __hip_bfloat16* __restrict__ proj, const __hip_bfloat16* __restrict__ projT,
    const __hip_bfloat16* __restrict__ qb, const float* __restrict__ psq,
    const float* __restrict__ qsq, float* __restrict__ outk, float* __restrict__ outv)
{
    __shared__ __hip_bfloat16 simbuf[2][32][72];
    __shared__ float otile[32][132];

    const int bid = blockIdx.x;
    const int b = bid & 7;         // XCD-pinned batch
    const int qt = bid >> 3;
    const int qrow0 = qt * 32;
    const int tid = threadIdx.x;
    const int w = tid >> 6;        // wave 0..3
    const int lane = tid & 63;
    const int lr = lane & 15, lh = lane >> 4;

    // q A-frags for the whole block (K=128 -> 4 ksteps, 2 mtiles)
    short8 aq[2][4];
    const __hip_bfloat16* qbase = qb + ((size_t)b * LQ + qrow0) * DD;
    #pragma unroll
    for (int mt = 0; mt < 2; ++mt)
        #pragma unroll
        for (int ks = 0; ks < 4; ++ks)
            aq[mt][ks] = *(const short8*)&qbase[(size_t)(mt * 16 + lr) * DD + ks * 32 + lh * 8];

    float qs[2][4];
    #pragma unroll
    for (int mt = 0; mt < 2; ++mt)
        #pragma unroll
        for (int r = 0; r < 4; ++r)
            qs[mt][r] = qsq[b * LQ + qrow0 + mt * 16 + lh * 4 + r];

    f4 oc[2][2] = {};   // [mtile][dtile], wave's d range = [w*32, w*32+32)

    const __hip_bfloat16* pjb = proj + (size_t)b * LL * DD;
    const __hip_bfloat16* ptb = projT + (size_t)b * DD * LL;
    const float* psb = psq + b * LL;

    for (int kt = 0; kt < LL / 64; ++kt) {
        const int keyw = kt * 64 + w * 16;   // this wave's 16 keys for GEMM1
        // ---- GEMM1: S[0:32][keyw:keyw+16] ----
        f4 s[2] = {};
        #pragma unroll
        for (int ks = 0; ks < 4; ++ks) {
            short8 bk = *(const short8*)&pjb[(size_t)(keyw + lr) * DD + ks * 32 + lh * 8];
            s[0] = __builtin_amdgcn_mfma_f32_16x16x32_bf16(aq[0][ks], bk, s[0], 0, 0, 0);
            s[1] = __builtin_amdgcn_mfma_f32_16x16x32_bf16(aq[1][ks], bk, s[1], 0, 0, 0);
        }
        // ---- transform -> sim (bf16) -> LDS ----
        const float pn = psb[keyw + lr];
        #pragma unroll
        for (int mt = 0; mt < 2; ++mt) {
            #pragma unroll
            for (int r = 0; r < 4; ++r) {
                float power = qs[mt][r] + pn - 2.0f * s[mt][r];
                float dist = sqrtf(fmaxf(power, 0.0f));
                float sim = __expf(-dist);
                simbuf[kt & 1][mt * 16 + lh * 4 + r][w * 16 + lr] = __float2bfloat16(sim);
            }
        }
        __syncthreads();
        // ---- GEMM2: O += sim @ proj (contract over 64 keys) ----
        const int kb = kt * 64;
        #pragma unroll
        for (int kk = 0; kk < 2; ++kk) {
            short8 sa0 = *(const short8*)&simbuf[kt & 1][lr][kk * 32 + lh * 8];
            short8 sa1 = *(const short8*)&simbuf[kt & 1][16 + lr][kk * 32 + lh * 8];
            #pragma unroll
            for (int dt = 0; dt < 2; ++dt) {
                short8 bv = *(const short8*)&ptb[(size_t)(w * 32 + dt * 16 + lr) * LL + kb + kk * 32 + lh * 8];
                oc[0][dt] = __builtin_amdgcn_mfma_f32_16x16x32_bf16(sa0, bv, oc[0][dt], 0, 0, 0);
                oc[1][dt] = __builtin_amdgcn_mfma_f32_16x16x32_bf16(sa1, bv, oc[1][dt], 0, 0, 0);
            }
        }
    }

    // ---- epilogue: transpose O through LDS for coalesced f32 stores ----
    __syncthreads();
    #pragma unroll
    for (int mt = 0; mt < 2; ++mt)
        #pragma unroll
        for (int dt = 0; dt < 2; ++dt)
            #pragma unroll
            for (int r = 0; r < 4; ++r)
                otile[mt * 16 + lh * 4 + r][w * 32 + dt * 16 + lr] = oc[mt][dt][r];
    __syncthreads();

    const int row = tid >> 3;
    const int c0 = (tid & 7) * 16;
    float* dk = outk + ((size_t)b * LQ + qrow0 + row) * DD + c0;
    float* dv = outv + ((size_t)b * LQ + qrow0 + row) * DD + c0;
    #pragma unroll
    for (int i = 0; i < 4; ++i) {
        f4 v = *(const f4*)&otile[row][c0 + i * 4];
        *(f4*)&dk[i * 4] = v;
        *(f4*)&dv[i * 4] = v;
    }
}

extern "C" void kernel_launch(void* const* d_in, const int* in_sizes, int n_in,
                              void* d_out, int out_size, void* d_ws, size_t ws_size,
                              hipStream_t stream) {
    const float* x = (const float*)d_in[0];
    const float* W = (const float*)d_in[1];
    const float* bias = (const float*)d_in[2];

    float* out = (float*)d_out;
    const size_t NQ = (size_t)NB * LQ * DD;    // 2,097,152 per output tensor
    float* qf = out;            // output 0: q
    float* outk = out + NQ;     // output 1: k
    float* outv = out + 2 * NQ; // output 2: v

    char* ws = (char*)d_ws;
    __hip_bfloat16* proj  = (__hip_bfloat16*)ws;                          // 8 MB
    __hip_bfloat16* projT = (__hip_bfloat16*)(ws + 8u * 1024 * 1024);     // 8 MB
    __hip_bfloat16* qb    = (__hip_bfloat16*)(ws + 16u * 1024 * 1024);    // 4 MB
    float* psq            = (float*)(ws + 20u * 1024 * 1024);             // 128 KB
    float* qsq            = (float*)(ws + 20u * 1024 * 1024 + 256u * 1024); // 64 KB

    hipLaunchKernelGGL(projA_kernel, dim3((NB * LL + NB * LQ) / 64), dim3(256), 0, stream,
                       x, W, bias, proj, projT, qb, qf, psq, qsq);
    hipLaunchKernelGGL(fused_kernel, dim3(NB * (LQ / 32)), dim3(256), 0, stream,
                       proj, projT, qb, psq, qsq, outk, outv);
}